// Round 8
// baseline (341.704 us; speedup 1.0000x reference)
//
#include <hip/hip_runtime.h>
#include <hip/hip_bf16.h>
#include <stdint.h>

#define NNODES 100000
#define HID 128
#define TSZ 32
#define MDIM 16
#define ES 600000
#define ED 600000
#define ETOT (ES + ED)
#define GN (2 * NNODES)     // both branches share one node index space
#define GNP 200704          // 196 * 1024, padded for the scan
#define SCAN_BLOCKS 196
#define NP8 (NNODES * 8)    // 800,000 packed pairs per branch
#define GN8 (GN * 8)        // 1,600,000 packed pairs total
#define PQ_BLOCKS 1563      // ceil(NNODES/64)
#define N4 (NNODES * 4)     // 400,000 round threads per branch
#define CNT_BLK 586         // ceil(600000/1024) count blocks per edge set

typedef unsigned short ushort_t;

__device__ __forceinline__ float bflo(unsigned u) { return __uint_as_float(u << 16); }
__device__ __forceinline__ float bfhi(unsigned u) { return __uint_as_float(u & 0xffff0000u); }

// RNE fp32 -> bf16 (finite inputs only)
__device__ __forceinline__ unsigned f2bf(float f) {
    unsigned u = __float_as_uint(f);
    return (u + 0x7FFFu + ((u >> 16) & 1u)) >> 16;
}
__device__ __forceinline__ unsigned packbf(float lo, float hi) {
    return f2bf(lo) | (f2bf(hi) << 16);
}

__device__ __forceinline__ float tanh_fast(float v) {
    float z = __expf(2.f * v);
    return 1.f - 2.f / (z + 1.f);
}

// ---------------------------------------------------------------- PQ (int8, step 1/32)
__global__ __launch_bounds__(256) void k_pq(const float* __restrict__ x,
                                            const float* __restrict__ Wt,
                                            const float* __restrict__ bt,
                                            char* __restrict__ pq) {
    __shared__ float xs[64][132];
    __shared__ float wl[64][130];
    const int tid = threadIdx.x;
    const int n0 = blockIdx.x * 64;

    for (int i = tid; i < 4096; i += 256) {
        int h = i >> 5, c = i & 31;
        float a = Wt[i];
        float b = Wt[4096 + i];
        wl[c][h] = a;
        wl[c + 32][h] = b;
    }
    const float4* xsrc = (const float4*)(x + (size_t)n0 * 128);
#pragma unroll
    for (int i = 0; i < 8; ++i) {
        int idx = tid + 256 * i;
        int node = idx >> 5;
        int rem = idx & 31;
        if (n0 + node < NNODES) {
            float4 v = xsrc[idx];
            *(float4*)&xs[node][rem * 4] = v;
        }
    }
    __syncthreads();

    const int l = tid & 63;
    const int w = tid >> 6;
    const int c0 = l & 15;
    const int ng = w * 16 + (l >> 4) * 4;
    float acc[4][4] = {};
#pragma unroll 4
    for (int h = 0; h < 128; h += 2) {
        float2 xv[4], wv[4];
#pragma unroll
        for (int m = 0; m < 4; ++m) xv[m] = *(const float2*)&xs[ng + m][h];
#pragma unroll
        for (int m = 0; m < 4; ++m) wv[m] = *(const float2*)&wl[c0 + 16 * m][h];
#pragma unroll
        for (int a = 0; a < 4; ++a)
#pragma unroll
            for (int b = 0; b < 4; ++b)
                acc[a][b] = fmaf(xv[a].y, wv[b].y, fmaf(xv[a].x, wv[b].x, acc[a][b]));
    }
    float bv[4];
#pragma unroll
    for (int b = 0; b < 4; ++b) {
        int c = c0 + 16 * b;
        bv[b] = (c < 32) ? bt[c] : 0.f;
    }
    __syncthreads();
    char* buf = (char*)&xs[0][0];
#pragma unroll
    for (int a = 0; a < 4; ++a) {
#pragma unroll
        for (int b = 0; b < 4; ++b) {
            float v = acc[a][b] + bv[b];
            int q = __float2int_rn(v * 32.f);
            q = max(-127, min(127, q));
            buf[(ng + a) * 64 + c0 + 16 * b] = (char)q;
        }
    }
    __syncthreads();
    uint4 v4 = ((const uint4*)buf)[tid];
    ((uint4*)(pq + (size_t)blockIdx.x * 4096))[tid] = v4;
}

// ---------------------------------------------------------------- init m + degree count (merged, block-range partitioned)
// blocks [0,3125): init m_a; [3125,3125+586): spatial count; [3711,4297): dom count.
__global__ __launch_bounds__(256) void k_initcount(const float* __restrict__ mask,
                                                   unsigned* __restrict__ m_a,
                                                   const int* __restrict__ sdst,
                                                   const int* __restrict__ ddst,
                                                   int* __restrict__ counts) {
    const int tid = threadIdx.x;
    int b = (int)blockIdx.x;
    if (b < 3125) {
        int idx = b * 256 + tid;           // < NP8 exactly
        float2 v = ((const float2*)mask)[idx];
        unsigned p = packbf(v.x, v.y);
        m_a[idx] = p;
        m_a[NP8 + idx] = p;
        return;
    }
    b -= 3125;
    const int* dst;
    int add;
    if (b < CNT_BLK) { dst = sdst; add = 0; }
    else { b -= CNT_BLK; dst = ddst; add = NNODES; }
    int e0 = (b * 256 + tid) * 4;
    if (e0 + 4 <= 600000) {
        int4 d = *(const int4*)(dst + e0);
        atomicAdd(&counts[d.x + add], 1);
        atomicAdd(&counts[d.y + add], 1);
        atomicAdd(&counts[d.z + add], 1);
        atomicAdd(&counts[d.w + add], 1);
    } else {
        for (int e = e0; e < 600000; ++e) atomicAdd(&counts[dst[e] + add], 1);
    }
}

// ---------------------------------------------------------------- fused scan (single kernel, arrive-and-spin)
// 196 blocks x 256 threads, 4 counts per thread. flag zeroed by memset each call.
__global__ __launch_bounds__(256) void k_scanfused(const int* __restrict__ counts,
                                                   int* __restrict__ bsum,
                                                   int* __restrict__ flag,
                                                   int* __restrict__ off,
                                                   int* __restrict__ cursor) {
    __shared__ int sh[256];
    const int tid = threadIdx.x;
    const int bid = (int)blockIdx.x;
    int4 v = ((const int4*)counts)[bid * 256 + tid];
    int tot = v.x + v.y + v.z + v.w;
    sh[tid] = tot;
    __syncthreads();
    for (int o = 1; o < 256; o <<= 1) {
        int add = (tid >= o) ? sh[tid - o] : 0;
        __syncthreads();
        sh[tid] += add;
        __syncthreads();
    }
    int incl = sh[tid];                     // inclusive within block
    if (tid == 255) bsum[bid] = incl;
    // arrive + spin until all blocks published bsum
    if (tid == 0) {
        __threadfence();
        atomicAdd(flag, 1);
        while (__hip_atomic_load(flag, __ATOMIC_RELAXED, __HIP_MEMORY_SCOPE_AGENT) < SCAN_BLOCKS) {}
        __threadfence();
    }
    __syncthreads();
    // scan the 196 block sums (every block redundantly)
    sh[tid] = (tid < SCAN_BLOCKS) ? bsum[tid] : 0;
    __syncthreads();
    for (int o = 1; o < 256; o <<= 1) {
        int add = (tid >= o) ? sh[tid - o] : 0;
        __syncthreads();
        sh[tid] += add;
        __syncthreads();
    }
    int base = (bid > 0) ? sh[bid - 1] : 0;
    int excl = base + incl - tot;
    int4 o4;
    o4.x = excl;
    o4.y = o4.x + v.x;
    o4.z = o4.y + v.y;
    o4.w = o4.z + v.z;
    ((int4*)off)[bid * 256 + tid] = o4;
    ((int4*)cursor)[bid * 256 + tid] = o4;
}

// ---------------------------------------------------------------- ew + CSR fill
__global__ void k_ewfill(const char* __restrict__ pq,
                         const int* __restrict__ ssrc, const int* __restrict__ sdst,
                         const int* __restrict__ dsrc, const int* __restrict__ ddst,
                         const float* __restrict__ sattr, const float* __restrict__ dattr,
                         const float* __restrict__ Wp, const float* __restrict__ bp,
                         const float* __restrict__ Wd, const float* __restrict__ bd,
                         int* __restrict__ cursor, unsigned* __restrict__ csr) {
    int e = blockIdx.x * 256 + threadIdx.x;
    if (e >= ETOT) return;
    int src, dst, dstg, srcg;
    float acc;
    const float* wt;
    if (e < ES) {
        src = ssrc[e];
        dst = sdst[e];
        dstg = dst;
        srcg = src;
        const float4 a = *(const float4*)(sattr + (size_t)e * 4);
        acc = bp[0] + a.x * Wp[0] + a.y * Wp[1] + a.z * Wp[2] + a.w * Wp[3];
        wt = Wp + 4;
    } else {
        int ed = e - ES;
        src = dsrc[ed];
        dst = ddst[ed];
        dstg = dst + NNODES;
        srcg = src + NNODES;
        acc = bd[0] + dattr[ed] * Wd[0];
        wt = Wd + 1;
    }
    const uint4* Pp = (const uint4*)(pq + (size_t)src * 64);
    const uint4* Qp = (const uint4*)(pq + (size_t)dst * 64 + 32);
    uint4 pa = Pp[0], pb = Pp[1];
    uint4 qa = Qp[0], qb = Qp[1];
    unsigned pw[8] = {pa.x, pa.y, pa.z, pa.w, pb.x, pb.y, pb.z, pb.w};
    unsigned qw[8] = {qa.x, qa.y, qa.z, qa.w, qb.x, qb.y, qb.z, qb.w};
#pragma unroll
    for (int d = 0; d < 8; ++d) {
        unsigned a = pw[d], b = qw[d];
#pragma unroll
        for (int k = 0; k < 4; ++k) {
            int pi = (int)(char)(a >> (8 * k));
            int qi = (int)(char)(b >> (8 * k));
            float t = tanh_fast((float)(pi + qi) * 0.03125f);
            acc = fmaf(t, wt[d * 4 + k], acc);
        }
    }
    float ew = 1.f / (1.f + __expf(-acc));
    unsigned entry = ((unsigned)srcg << 14) | (unsigned)(ew * 16383.f + 0.5f);
    int pos = atomicAdd(&cursor[dstg], 1);
    csr[pos] = entry;
}

// ---------------------------------------------------------------- propagation round (both branches, 4 thr/node, 2 chains each)
template <int TAG>
__global__ __launch_bounds__(256) void k_round_t(const unsigned* __restrict__ m_in,
                                                 unsigned* __restrict__ m_out,
                                                 const int* __restrict__ off,
                                                 const unsigned* __restrict__ csr) {
    int idx = blockIdx.x * 256 + threadIdx.x;   // 3125*256 = 800000 exact
    int g = idx >> 2;
    int jp = idx & 3;
    int mi = g * 8 + jp;
    int p0 = off[g], p1 = off[g + 1];
    unsigned c0 = m_in[mi], c1 = m_in[mi + 4];
    float a0 = bflo(c0), b0 = bfhi(c0);
    float a1 = bflo(c1), b1 = bfhi(c1);
    int p = p0;
    for (; p + 1 < p1; p += 2) {
        unsigned e0 = csr[p], e1 = csr[p + 1];
        unsigned s0 = (e0 >> 14) * 8 + jp, s1 = (e1 >> 14) * 8 + jp;
        unsigned m00 = m_in[s0], m01 = m_in[s0 + 4];
        unsigned m10 = m_in[s1], m11 = m_in[s1 + 4];
        float w0 = (float)(e0 & 16383u) * (1.f / 16383.f);
        float w1 = (float)(e1 & 16383u) * (1.f / 16383.f);
        a0 = fmaxf(a0, fmaxf(bflo(m00) * w0, bflo(m10) * w1));
        b0 = fmaxf(b0, fmaxf(bfhi(m00) * w0, bfhi(m10) * w1));
        a1 = fmaxf(a1, fmaxf(bflo(m01) * w0, bflo(m11) * w1));
        b1 = fmaxf(b1, fmaxf(bfhi(m01) * w0, bfhi(m11) * w1));
    }
    if (p < p1) {
        unsigned e0 = csr[p];
        unsigned s0 = (e0 >> 14) * 8 + jp;
        unsigned m00 = m_in[s0], m01 = m_in[s0 + 4];
        float w0 = (float)(e0 & 16383u) * (1.f / 16383.f);
        a0 = fmaxf(a0, bflo(m00) * w0);
        b0 = fmaxf(b0, bfhi(m00) * w0);
        a1 = fmaxf(a1, bflo(m01) * w0);
        b1 = fmaxf(b1, bfhi(m01) * w0);
    }
    m_out[mi] = packbf(a0, b0);
    m_out[mi + 4] = packbf(a1, b1);
}

// ---------------------------------------------------------------- final round fused with branch combine
__global__ __launch_bounds__(256) void k_round_final(const unsigned* __restrict__ m_in,
                                                     float* __restrict__ out,
                                                     const int* __restrict__ off,
                                                     const unsigned* __restrict__ csr) {
    int idx = blockIdx.x * 256 + threadIdx.x;
    if (idx >= N4) return;
    int g = idx >> 2;
    int jp = idx & 3;
    float a0, b0, a1, b1;
    {
        int mi = g * 8 + jp;
        unsigned c0 = m_in[mi], c1 = m_in[mi + 4];
        a0 = bflo(c0); b0 = bfhi(c0);
        a1 = bflo(c1); b1 = bfhi(c1);
    }
    {
        int p0 = off[g], p1 = off[g + 1];
        for (int p = p0; p < p1; ++p) {
            unsigned e0 = csr[p];
            unsigned s0 = (e0 >> 14) * 8 + jp;
            unsigned m00 = m_in[s0], m01 = m_in[s0 + 4];
            float w0 = (float)(e0 & 16383u) * (1.f / 16383.f);
            a0 = fmaxf(a0, bflo(m00) * w0);
            b0 = fmaxf(b0, bfhi(m00) * w0);
            a1 = fmaxf(a1, bflo(m01) * w0);
            b1 = fmaxf(b1, bfhi(m01) * w0);
        }
    }
    {
        int mi2 = (g + NNODES) * 8 + jp;
        unsigned c0 = m_in[mi2], c1 = m_in[mi2 + 4];
        a0 = fmaxf(a0, bflo(c0)); b0 = fmaxf(b0, bfhi(c0));
        a1 = fmaxf(a1, bflo(c1)); b1 = fmaxf(b1, bfhi(c1));
        int g2 = g + NNODES;
        int p0 = off[g2], p1 = off[g2 + 1];
        for (int p = p0; p < p1; ++p) {
            unsigned e0 = csr[p];
            unsigned s0 = (e0 >> 14) * 8 + jp;
            unsigned m00 = m_in[s0], m01 = m_in[s0 + 4];
            float w0 = (float)(e0 & 16383u) * (1.f / 16383.f);
            a0 = fmaxf(a0, bflo(m00) * w0);
            b0 = fmaxf(b0, bfhi(m00) * w0);
            a1 = fmaxf(a1, bflo(m01) * w0);
            b1 = fmaxf(b1, bfhi(m01) * w0);
        }
    }
    *(float2*)&out[g * 16 + jp * 2] = make_float2(a0, b0);
    *(float2*)&out[g * 16 + jp * 2 + 8] = make_float2(a1, b1);
}

extern "C" void kernel_launch(void* const* d_in, const int* in_sizes, int n_in,
                              void* d_out, int out_size, void* d_ws, size_t ws_size,
                              hipStream_t stream) {
    const float* x     = (const float*)d_in[0];
    const float* mask  = (const float*)d_in[1];
    const int*   sei   = (const int*)d_in[2];
    const int*   dei   = (const int*)d_in[3];
    const float* sattr = (const float*)d_in[4];
    const float* dattr = (const float*)d_in[5];
    const float* Wt    = (const float*)d_in[6];
    const float* bt    = (const float*)d_in[7];
    const float* Wp    = (const float*)d_in[8];
    const float* bp    = (const float*)d_in[9];
    const float* Wd    = (const float*)d_in[10];
    const float* bd    = (const float*)d_in[11];
    float* out = (float*)d_out;

    char* ws = (char*)d_ws;
    size_t o = 0;
    auto take = [&](size_t bytes) -> char* {
        char* p = ws + o;
        o = (o + bytes + 255) & ~(size_t)255;
        return p;
    };
    char* pq      = take((size_t)PQ_BLOCKS * 4096);
    int* counts   = (int*)take((size_t)GNP * 4 + 256);  // flag lives right after counts
    int* flag     = counts + GNP;
    int* off      = (int*)take((size_t)GNP * 4);
    int* cursor   = (int*)take((size_t)GNP * 4);
    int* bsum     = (int*)take(256 * 4);
    unsigned* csr = (unsigned*)take((size_t)ETOT * 4);
    unsigned* m_a = (unsigned*)take((size_t)GN8 * 4);
    unsigned* m_b = (unsigned*)take((size_t)GN8 * 4);

    hipMemsetAsync(counts, 0, (size_t)GNP * 4 + 256, stream);
    k_pq<<<PQ_BLOCKS, 256, 0, stream>>>(x, Wt, bt, pq);
    k_initcount<<<3125 + 2 * CNT_BLK, 256, 0, stream>>>(mask, m_a, sei + ES, dei + ED, counts);
    k_scanfused<<<SCAN_BLOCKS, 256, 0, stream>>>(counts, bsum, flag, off, cursor);
    k_ewfill<<<(ETOT + 255) / 256, 256, 0, stream>>>(pq,
        sei, sei + ES, dei, dei + ED, sattr, dattr, Wp, bp, Wd, bd, cursor, csr);
    k_round_t<0><<<3125, 256, 0, stream>>>(m_a, m_b, off, csr);
    k_round_t<1><<<3125, 256, 0, stream>>>(m_b, m_a, off, csr);
    k_round_final<<<1563, 256, 0, stream>>>(m_a, out, off, csr);
}